// Round 1
// baseline (1133.573 us; speedup 1.0000x reference)
//
#include <hip/hip_runtime.h>
#include <hip/hip_bf16.h>

// ---------------------------------------------------------------------------
// GINE 2-layer GNN, MI355X (gfx950)
// Pipeline per layer:
//   edge_kernel : ea = edge_attr @ We^T (bf16 MFMA) ; m = relu(x[src]+ea+be)
//                 atomicAdd into agg[dst]
//   mlp1_kernel : t = (agg + x) @ W1^T + b1
//   bnstats     : per-feature sum/sumsq over N
//   bnfinal     : scale/shift from batch stats
//   mlp2_kernel : out = relu(bn(t)) @ W2^T + b2  (+relu between layers)
// ---------------------------------------------------------------------------

typedef short short8 __attribute__((ext_vector_type(8)));
typedef float f32x4 __attribute__((ext_vector_type(4)));

__device__ __forceinline__ short f2bf(float x) {
    unsigned u = __float_as_uint(x);
    unsigned r = (u + 0x7fffu + ((u >> 16) & 1u)) >> 16;   // RTNE
    return (short)r;
}

// ---------------------------------------------------------------------------
// Edge kernel: one wave handles 16 edges x D features.
// A-frag (edges):  lane l holds edge_attr[e0 + (l&15)][(l>>4)*8 + j], j=0..7
// B-frag (We):     lane l holds We[fc*16 + (l&15)][(l>>4)*8 + j]  (bf16)
// C layout:        col = lane&15 (feature), row = (lane>>4)*4 + reg (edge)
// ---------------------------------------------------------------------------
template<int D>
__global__ __launch_bounds__(256) void edge_kernel(
    const float* __restrict__ x,      // [N][D]
    const int*   __restrict__ ei,     // [2][E]
    const float* __restrict__ eattr,  // [E][64]
    const short* __restrict__ WeB,    // [D][64] bf16
    const float* __restrict__ be,     // [D]
    float*       __restrict__ agg,    // [N][D]
    int E)
{
    const int wave = threadIdx.x >> 6;
    const int lane = threadIdx.x & 63;
    const int ebase = (blockIdx.x * 4 + wave) * 16;
    if (ebase >= E) return;
    const int g = lane >> 4;        // 0..3
    const int c = lane & 15;        // 0..15

    // --- A fragments (2 k-tiles of 32) ---
    int arow_e = ebase + c; if (arow_e >= E) arow_e = E - 1;
    const float* arow = eattr + (size_t)arow_e * 64 + g * 8;
    short8 afr[2];
#pragma unroll
    for (int kt = 0; kt < 2; ++kt) {
        f32x4 a0 = *(const f32x4*)(arow + kt * 32);
        f32x4 a1 = *(const f32x4*)(arow + kt * 32 + 4);
        short8 t;
        t[0] = f2bf(a0[0]); t[1] = f2bf(a0[1]); t[2] = f2bf(a0[2]); t[3] = f2bf(a0[3]);
        t[4] = f2bf(a1[0]); t[5] = f2bf(a1[1]); t[6] = f2bf(a1[2]); t[7] = f2bf(a1[3]);
        afr[kt] = t;
    }

    // --- src/dst for this lane's 4 output rows (edges) ---
    int se[4], de[4], ev[4];
#pragma unroll
    for (int r = 0; r < 4; ++r) {
        int e = ebase + g * 4 + r;
        ev[r] = e;
        int esafe = (e < E) ? e : (E - 1);
        se[r] = ei[esafe];
        de[r] = ei[E + esafe];
    }

    constexpr int FC = D / 16;
#pragma unroll
    for (int fc = 0; fc < FC; ++fc) {
        const short* brow = WeB + (size_t)(fc * 16 + c) * 64 + g * 8;
        short8 b0 = *(const short8*)(brow);
        short8 b1 = *(const short8*)(brow + 32);
        f32x4 acc = {0.f, 0.f, 0.f, 0.f};
        acc = __builtin_amdgcn_mfma_f32_16x16x32_bf16(afr[0], b0, acc, 0, 0, 0);
        acc = __builtin_amdgcn_mfma_f32_16x16x32_bf16(afr[1], b1, acc, 0, 0, 0);
        const int f = fc * 16 + c;
        const float bev = be[f];
#pragma unroll
        for (int r = 0; r < 4; ++r) {
            if (ev[r] < E) {
                float m = acc[r] + bev + x[(size_t)se[r] * D + f];
                m = fmaxf(m, 0.f);
                atomicAdd(&agg[(size_t)de[r] * D + f], m);
            }
        }
    }
}

// ---------------------------------------------------------------------------
// mlp1: t[n][f] = b1[f] + sum_k (agg[n][k] + x[n][k]) * W1[f][k]
// ---------------------------------------------------------------------------
template<int D>
__global__ __launch_bounds__(256) void mlp1_kernel(
    const float* __restrict__ agg, const float* __restrict__ x,
    const float* __restrict__ W1, const float* __restrict__ b1,
    float* __restrict__ t, int N)
{
    int gid = blockIdx.x * 256 + threadIdx.x;
    int n = gid >> 6, f = gid & 63;
    if (n >= N) return;
    const f32x4* ar = (const f32x4*)(agg + (size_t)n * D);
    const f32x4* xr = (const f32x4*)(x + (size_t)n * D);
    const f32x4* wr = (const f32x4*)(W1 + (size_t)f * D);
    float acc = b1[f];
#pragma unroll
    for (int k = 0; k < D / 4; ++k) {
        f32x4 a = ar[k], xx = xr[k], w = wr[k];
        acc += (a[0] + xx[0]) * w[0] + (a[1] + xx[1]) * w[1]
             + (a[2] + xx[2]) * w[2] + (a[3] + xx[3]) * w[3];
    }
    t[gid] = acc;
}

// ---------------------------------------------------------------------------
// BN stats: each lane owns feature f = tid&63 (stride 256 keeps f constant)
// ---------------------------------------------------------------------------
__global__ __launch_bounds__(256) void bnstats_kernel(
    const float* __restrict__ t, float* __restrict__ sums, int total)
{
    int tid = threadIdx.x;
    float s = 0.f, s2 = 0.f;
    for (int i = blockIdx.x * 256 + tid; i < total; i += gridDim.x * 256) {
        float v = t[i];
        s += v; s2 += v * v;
    }
    __shared__ float ls[256], ls2[256];
    ls[tid] = s; ls2[tid] = s2;
    __syncthreads();
    if (tid < 64) {
        s  = ls[tid]  + ls[tid + 64]  + ls[tid + 128]  + ls[tid + 192];
        s2 = ls2[tid] + ls2[tid + 64] + ls2[tid + 128] + ls2[tid + 192];
        atomicAdd(&sums[tid], s);
        atomicAdd(&sums[64 + tid], s2);
    }
}

__global__ void bnfinal_kernel(const float* __restrict__ sums,
                               const float* __restrict__ g,
                               const float* __restrict__ bb,
                               float* __restrict__ scsh, float invN)
{
    int f = threadIdx.x;  // 64 threads
    float mean = sums[f] * invN;
    float var  = sums[64 + f] * invN - mean * mean;
    float sc = g[f] * rsqrtf(var + 1e-5f);
    scsh[f] = sc;
    scsh[64 + f] = bb[f] - mean * sc;
}

// ---------------------------------------------------------------------------
// mlp2: h = relu(t*scale+shift); out = h @ W2^T + b2 (+optional relu)
// Block = 4 nodes; h staged in LDS.
// ---------------------------------------------------------------------------
__global__ __launch_bounds__(256) void mlp2_kernel(
    const float* __restrict__ t, const float* __restrict__ scsh,
    const float* __restrict__ W2, const float* __restrict__ b2,
    float* __restrict__ out, int N, int relu_out)
{
    __shared__ __align__(16) float hs[4][64];
    int tid = threadIdx.x;
    int nl = tid >> 6, k = tid & 63;
    int n = blockIdx.x * 4 + nl;
    float h = 0.f;
    if (n < N) h = fmaxf(t[(size_t)n * 64 + k] * scsh[k] + scsh[64 + k], 0.f);
    hs[nl][k] = h;
    __syncthreads();
    if (n >= N) return;
    const int f = k;
    const f32x4* wr = (const f32x4*)(W2 + (size_t)f * 64);
    const f32x4* hr = (const f32x4*)(hs[nl]);
    float acc = b2[f];
#pragma unroll
    for (int kk = 0; kk < 16; ++kk) {
        f32x4 w = wr[kk], hh = hr[kk];
        acc += hh[0] * w[0] + hh[1] * w[1] + hh[2] * w[2] + hh[3] * w[3];
    }
    if (relu_out) acc = fmaxf(acc, 0.f);
    out[(size_t)n * 64 + f] = acc;
}

// ---------------------------------------------------------------------------
// Weight prep: f32 -> bf16 for We0 (128x64) and We1 (64x64)
// ---------------------------------------------------------------------------
__global__ __launch_bounds__(256) void prep_kernel(
    const float* __restrict__ We0, const float* __restrict__ We1,
    short* __restrict__ WeB0, short* __restrict__ WeB1)
{
    int i = blockIdx.x * 256 + threadIdx.x;
    if (i < 128 * 64) WeB0[i] = f2bf(We0[i]);
    if (i < 64 * 64)  WeB1[i] = f2bf(We1[i]);
}

extern "C" void kernel_launch(void* const* d_in, const int* in_sizes, int n_in,
                              void* d_out, int out_size, void* d_ws, size_t ws_size,
                              hipStream_t stream)
{
    (void)n_in; (void)out_size; (void)ws_size;
    const float* x     = (const float*)d_in[0];
    const int*   ei    = (const int*)d_in[1];
    const float* eattr = (const float*)d_in[2];
    const float* We0   = (const float*)d_in[3];
    const float* be0   = (const float*)d_in[4];
    const float* W1_0  = (const float*)d_in[5];
    const float* b1_0  = (const float*)d_in[6];
    const float* g0    = (const float*)d_in[7];
    const float* bb0   = (const float*)d_in[8];
    const float* W2_0  = (const float*)d_in[9];
    const float* b2_0  = (const float*)d_in[10];
    const float* We1   = (const float*)d_in[11];
    const float* be1   = (const float*)d_in[12];
    const float* W1_1  = (const float*)d_in[13];
    const float* b1_1  = (const float*)d_in[14];
    const float* g1    = (const float*)d_in[15];
    const float* bb1   = (const float*)d_in[16];
    const float* W2_1  = (const float*)d_in[17];
    const float* b2_1  = (const float*)d_in[18];
    float* out = (float*)d_out;

    const int N = in_sizes[0] / 128;   // 50000
    const int E = in_sizes[2] / 64;    // 800000

    char* ws = (char*)d_ws;
    float* agg0 = (float*)ws;                          // N*128 f32
    float* agg1 = (float*)(ws + (size_t)N * 128 * 4);  // N*64 f32
    float* tbuf = agg1 + (size_t)N * 64;               // N*64 f32
    float* y0   = tbuf + (size_t)N * 64;               // N*64 f32
    short* WeB0 = (short*)(y0 + (size_t)N * 64);       // 128*64 bf16
    short* WeB1 = WeB0 + 128 * 64;                     // 64*64 bf16
    float* stats = (float*)(WeB1 + 64 * 64);
    float* sum0  = stats;          // [128] sum+sumsq
    float* scsh0 = stats + 128;    // [128] scale+shift
    float* sum1  = stats + 256;
    float* scsh1 = stats + 384;

    hipMemsetAsync(agg0, 0, (size_t)N * 128 * 4, stream);
    hipMemsetAsync(agg1, 0, (size_t)N * 64 * 4, stream);
    hipMemsetAsync(stats, 0, 512 * 4, stream);
    prep_kernel<<<32, 256, 0, stream>>>(We0, We1, WeB0, WeB1);

    const int edge_blocks = (E + 63) / 64;
    const int nf_blocks   = (N * 64 + 255) / 256;
    const int n4_blocks   = (N + 3) / 4;

    // ----- layer 0 -----
    edge_kernel<128><<<edge_blocks, 256, 0, stream>>>(x, ei, eattr, WeB0, be0, agg0, E);
    mlp1_kernel<128><<<nf_blocks, 256, 0, stream>>>(agg0, x, W1_0, b1_0, tbuf, N);
    bnstats_kernel<<<256, 256, 0, stream>>>(tbuf, sum0, N * 64);
    bnfinal_kernel<<<1, 64, 0, stream>>>(sum0, g0, bb0, scsh0, 1.0f / N);
    mlp2_kernel<<<n4_blocks, 256, 0, stream>>>(tbuf, scsh0, W2_0, b2_0, y0, N, 1);

    // ----- layer 1 -----
    edge_kernel<64><<<edge_blocks, 256, 0, stream>>>(y0, ei, eattr, WeB1, be1, agg1, E);
    mlp1_kernel<64><<<nf_blocks, 256, 0, stream>>>(agg1, y0, W1_1, b1_1, tbuf, N);
    bnstats_kernel<<<256, 256, 0, stream>>>(tbuf, sum1, N * 64);
    bnfinal_kernel<<<1, 64, 0, stream>>>(sum1, g1, bb1, scsh1, 1.0f / N);
    mlp2_kernel<<<n4_blocks, 256, 0, stream>>>(tbuf, scsh1, W2_1, b2_1, out, N, 0);
}